// Round 1
// baseline (414.745 us; speedup 1.0000x reference)
//
#include <hip/hip_runtime.h>
#include <math.h>

#define NN 16384
#define IN_DIM 4
#define HID 64
#define OUT_DIM 2
#define SPLITS 4
#define KCH (NN / SPLITS)   // 4096

typedef __bf16 bf16x8 __attribute__((ext_vector_type(8)));
typedef float  f32x4  __attribute__((ext_vector_type(4)));

// ---------------------------------------------------------------------------
// Kernel 1: messages = tanh(x@W1+b1)@W2+b2, stored TRANSPOSED as bf16:
// msgT[h][node], h<64, node<16384. 64 nodes per block, 256 blocks.
// ---------------------------------------------------------------------------
__global__ __launch_bounds__(256) void k_messages(
    const float* __restrict__ x, const float* __restrict__ W1,
    const float* __restrict__ b1, const float* __restrict__ W2,
    const float* __restrict__ b2, __bf16* __restrict__ msgT)
{
    __shared__ float  xs[64 * 4];
    __shared__ float  h1[64 * 64];     // [node][h]; writes lane-stride-1, reads broadcast
    __shared__ __bf16 mt[64 * 66];     // [h][node], pad 66 -> write banks distinct

    const int t = threadIdx.x;
    const int node0 = blockIdx.x * 64;
    xs[t] = x[node0 * 4 + t];
    __syncthreads();

    const int h = t & 63, g = t >> 6;
    for (int n = g * 16; n < g * 16 + 16; ++n) {
        float acc = b1[h];
        #pragma unroll
        for (int k = 0; k < 4; ++k) acc += xs[n * 4 + k] * W1[k * 64 + h];
        h1[n * 64 + h] = tanhf(acc);
    }
    __syncthreads();
    for (int n = g * 16; n < g * 16 + 16; ++n) {
        float acc = b2[h];
        #pragma unroll 8
        for (int k = 0; k < 64; ++k) acc += h1[n * 64 + k] * W2[k * 64 + h];
        mt[h * 66 + n] = (__bf16)acc;
    }
    __syncthreads();
    // coalesced 16B stores: 64 rows x 8 chunks of 8 elems = 512 slots
    for (int slot = t; slot < 512; slot += 256) {
        const int r = slot >> 3, c = (slot & 7) * 8;
        bf16x8 v;
        #pragma unroll
        for (int j = 0; j < 8; ++j) v[j] = mt[r * 66 + c + j];
        *(bf16x8*)(msgT + (size_t)r * NN + node0 + c) = v;
    }
}

// ---------------------------------------------------------------------------
// Kernel 2: part[s] += adj[rows, kchunk] @ messages[kchunk, :]  (bf16 MFMA)
// 1024 blocks x 256 thr. block b: s = b>>8, rowblk = b&255 (64 rows).
// Wave w: rows rowblk*64 + w*16 .. +16, all 64 cols, K over its 4096 chunk.
// MFMA 16x16x32 bf16; A = adj tile (fp32 -> bf16 in-register), B = msgT.
// A-frag lane l: row = l&15, k = 8*(l>>4)+j. B-frag: col = l&15, same k.
// D lane l: col = l&15, row = 4*(l>>4)+j.
// ---------------------------------------------------------------------------
__global__ __launch_bounds__(256) void k_agg(
    const float* __restrict__ adj, const __bf16* __restrict__ msgT,
    float* __restrict__ part)
{
    const int t = threadIdx.x;
    const int wave = t >> 6, lane = t & 63;
    const int s = blockIdx.x >> 8;
    const int rowblk = blockIdx.x & 255;
    const int m0 = rowblk * 64 + wave * 16;
    const int c = lane & 15;
    const int kg = lane >> 4;

    const float*  ap = adj  + (size_t)(m0 + c) * NN + s * KCH + kg * 8;
    const __bf16* bp = msgT + (size_t)c * NN        + s * KCH + kg * 8;

    f32x4 acc0 = {}, acc1 = {}, acc2 = {}, acc3 = {};

    #pragma unroll 2
    for (int kk = 0; kk < KCH / 32; ++kk) {
        f32x4 a0 = *(const f32x4*)(ap);
        f32x4 a1 = *(const f32x4*)(ap + 4);
        ap += 32;
        bf16x8 b0v = *(const bf16x8*)(bp);
        bf16x8 b1v = *(const bf16x8*)(bp + 16 * (size_t)NN);
        bf16x8 b2v = *(const bf16x8*)(bp + 32 * (size_t)NN);
        bf16x8 b3v = *(const bf16x8*)(bp + 48 * (size_t)NN);
        bp += 32;
        bf16x8 af;
        af[0] = (__bf16)a0[0]; af[1] = (__bf16)a0[1];
        af[2] = (__bf16)a0[2]; af[3] = (__bf16)a0[3];
        af[4] = (__bf16)a1[0]; af[5] = (__bf16)a1[1];
        af[6] = (__bf16)a1[2]; af[7] = (__bf16)a1[3];
        acc0 = __builtin_amdgcn_mfma_f32_16x16x32_bf16(af, b0v, acc0, 0, 0, 0);
        acc1 = __builtin_amdgcn_mfma_f32_16x16x32_bf16(af, b1v, acc1, 0, 0, 0);
        acc2 = __builtin_amdgcn_mfma_f32_16x16x32_bf16(af, b2v, acc2, 0, 0, 0);
        acc3 = __builtin_amdgcn_mfma_f32_16x16x32_bf16(af, b3v, acc3, 0, 0, 0);
    }

    float* pp = part + (size_t)s * NN * HID;
    const int rbase = m0 + (lane >> 4) * 4;
    const int cbase = lane & 15;
    f32x4 accs[4] = {acc0, acc1, acc2, acc3};
    #pragma unroll
    for (int tt = 0; tt < 4; ++tt) {
        #pragma unroll
        for (int j = 0; j < 4; ++j) {
            pp[(size_t)(rbase + j) * HID + tt * 16 + cbase] = accs[tt][j];
        }
    }
}

// ---------------------------------------------------------------------------
// Kernel 3: agg = sum(part[0..3]); combined=[x,agg];
// out = (tanh(tanh(combined@U1+c1)@U2+c2)) @ Wo + bo.  64 nodes/block.
// ---------------------------------------------------------------------------
__global__ __launch_bounds__(256) void k_update(
    const float* __restrict__ x, const float* __restrict__ part,
    const float* __restrict__ U1, const float* __restrict__ c1,
    const float* __restrict__ U2, const float* __restrict__ c2,
    const float* __restrict__ Wo, const float* __restrict__ bo,
    float* __restrict__ out)
{
    __shared__ float comb[64 * 73];  // [node][0..3]=x, [4..67]=agg; later h2 in [0..63]
    __shared__ float h1s[64 * 66];

    const int t = threadIdx.x, h = t & 63, g = t >> 6;
    const int node0 = blockIdx.x * 64;

    comb[(t >> 2) * 73 + (t & 3)] = x[node0 * 4 + t];
    const float* P0 = part;
    const float* P1 = part + (size_t)1 * NN * HID;
    const float* P2 = part + (size_t)2 * NN * HID;
    const float* P3 = part + (size_t)3 * NN * HID;
    for (int n = g * 16; n < g * 16 + 16; ++n) {
        const size_t idx = (size_t)(node0 + n) * HID + h;
        comb[n * 73 + 4 + h] = P0[idx] + P1[idx] + P2[idx] + P3[idx];
    }
    __syncthreads();
    for (int n = g * 16; n < g * 16 + 16; ++n) {
        float acc = c1[h];
        #pragma unroll 4
        for (int k = 0; k < 68; ++k) acc += comb[n * 73 + k] * U1[k * 64 + h];
        h1s[n * 66 + h] = tanhf(acc);
    }
    __syncthreads();
    for (int n = g * 16; n < g * 16 + 16; ++n) {
        float acc = c2[h];
        #pragma unroll 8
        for (int k = 0; k < 64; ++k) acc += h1s[n * 66 + k] * U2[k * 64 + h];
        comb[n * 73 + h] = tanhf(acc);  // h2 overwrites low cols (comb reads all done)
    }
    __syncthreads();
    if (t < 128) {
        const int n = t >> 1, o = t & 1;
        float acc = bo[o];
        #pragma unroll 8
        for (int k = 0; k < 64; ++k) acc += comb[n * 73 + k] * Wo[k * 2 + o];
        out[(size_t)(node0 + n) * 2 + o] = acc;
    }
}

// ---------------------------------------------------------------------------
extern "C" void kernel_launch(void* const* d_in, const int* in_sizes, int n_in,
                              void* d_out, int out_size, void* d_ws, size_t ws_size,
                              hipStream_t stream)
{
    const float* x   = (const float*)d_in[0];
    const float* adj = (const float*)d_in[1];
    const float* W1  = (const float*)d_in[2];
    const float* b1  = (const float*)d_in[3];
    const float* W2  = (const float*)d_in[4];
    const float* b2  = (const float*)d_in[5];
    const float* U1  = (const float*)d_in[6];
    const float* c1  = (const float*)d_in[7];
    const float* U2  = (const float*)d_in[8];
    const float* c2  = (const float*)d_in[9];
    const float* Wo  = (const float*)d_in[10];
    const float* bo  = (const float*)d_in[11];
    float* out = (float*)d_out;

    // workspace layout: [msgT: 64*16384 bf16 = 2 MB][part: 4*16384*64 f32 = 16 MB]
    __bf16* msgT = (__bf16*)d_ws;
    float*  part = (float*)((char*)d_ws + (size_t)HID * NN * sizeof(__bf16));

    k_messages<<<NN / 64, 256, 0, stream>>>(x, W1, b1, W2, b2, msgT);
    k_agg<<<256 * SPLITS, 256, 0, stream>>>(adj, msgT, part);
    k_update<<<NN / 64, 256, 0, stream>>>(x, part, U1, c1, U2, c2, Wo, bo, out);
}

// Round 2
// 357.467 us; speedup vs baseline: 1.1602x; 1.1602x over previous
//
#include <hip/hip_runtime.h>
#include <math.h>

#define NN 16384
#define IN_DIM 4
#define HID 64
#define OUT_DIM 2
#define SPLITS 4
#define KCH (NN / SPLITS)   // 4096
#define BK 64
#define NT (KCH / BK)       // 64

typedef __bf16 bf16x8 __attribute__((ext_vector_type(8)));
typedef float  f32x4  __attribute__((ext_vector_type(4)));

__device__ __forceinline__ void gload_lds16(const float* g, void* lds) {
    __builtin_amdgcn_global_load_lds(
        (const __attribute__((address_space(1))) void*)g,
        (__attribute__((address_space(3))) void*)lds, 16, 0, 0);
}

// ---------------------------------------------------------------------------
// Kernel 1: messages = tanh(x@W1+b1)@W2+b2, stored TRANSPOSED as bf16:
// msgT[h][node]. 64 nodes per block, 256 blocks.
// ---------------------------------------------------------------------------
__global__ __launch_bounds__(256) void k_messages(
    const float* __restrict__ x, const float* __restrict__ W1,
    const float* __restrict__ b1, const float* __restrict__ W2,
    const float* __restrict__ b2, __bf16* __restrict__ msgT)
{
    __shared__ float  xs[64 * 4];
    __shared__ float  h1[64 * 64];
    __shared__ __bf16 mt[64 * 66];

    const int t = threadIdx.x;
    const int node0 = blockIdx.x * 64;
    xs[t] = x[node0 * 4 + t];
    __syncthreads();

    const int h = t & 63, g = t >> 6;
    for (int n = g * 16; n < g * 16 + 16; ++n) {
        float acc = b1[h];
        #pragma unroll
        for (int k = 0; k < 4; ++k) acc += xs[n * 4 + k] * W1[k * 64 + h];
        h1[n * 64 + h] = tanhf(acc);
    }
    __syncthreads();
    for (int n = g * 16; n < g * 16 + 16; ++n) {
        float acc = b2[h];
        #pragma unroll 8
        for (int k = 0; k < 64; ++k) acc += h1[n * 64 + k] * W2[k * 64 + h];
        mt[h * 66 + n] = (__bf16)acc;
    }
    __syncthreads();
    for (int slot = t; slot < 512; slot += 256) {
        const int r = slot >> 3, c = (slot & 7) * 8;
        bf16x8 v;
        #pragma unroll
        for (int j = 0; j < 8; ++j) v[j] = mt[r * 66 + c + j];
        *(bf16x8*)(msgT + (size_t)r * NN + node0 + c) = v;
    }
}

// ---------------------------------------------------------------------------
// Kernel 2: part[s] = adj[rowblk rows, K-chunk s] @ messages  via bf16 MFMA.
// 1024 blocks x 256 thr (4 waves). Block: 64 rows x 64 cols, K over 4096.
// A staged in LDS via global_load_lds (width 16), double-buffered, BK=64.
// LDS layout: As[buf][row][p] where physical 16B-chunk p holds logical
// chunk c = p ^ (row&15)  (XOR swizzle, applied on BOTH global-src and
// ds_read sides; global_load_lds dest stays linear).
// MFMA 16x16x32 bf16: A-frag lane l: row=l&15, k=8*(l>>4)+j.
// D lane l: col=l&15, row=4*(l>>4)+j.
// ---------------------------------------------------------------------------
__global__ __launch_bounds__(256) void k_agg(
    const float* __restrict__ adj, const __bf16* __restrict__ msgT,
    float* __restrict__ part)
{
    __shared__ float As[2][64 * 64];   // 2 x 16 KB

    const int t = threadIdx.x;
    const int wave = t >> 6, lane = t & 63;
    const int s = blockIdx.x >> 8;
    const int rowblk = blockIdx.x & 255;
    const int m0 = rowblk * 64;
    const int k0 = s * KCH;

    // ---- staging addressing (pre-swizzled global source) ----
    const int trow = t >> 4;                 // 0..15 (row within 16-row round)
    const int tcol = t & 15;                 // physical chunk p
    const int cchunk = tcol ^ trow;          // logical chunk (swizzle involution)
    const float* src0 = adj + (size_t)(m0 + trow) * NN + k0 + cchunk * 4;
    const size_t rstep = (size_t)16 * NN;    // +16 rows per round

    // ---- fragment addressing ----
    const int r15 = lane & 15;
    const int kg  = lane >> 4;
    const int arow = wave * 16 + r15;        // fragment row within 64
    const __bf16* bp = msgT + (size_t)r15 * NN + k0 + kg * 8;

    f32x4 acc0 = {}, acc1 = {}, acc2 = {}, acc3 = {};

    // prologue: stage tile 0 into buffer 0
    #pragma unroll
    for (int r = 0; r < 4; ++r)
        gload_lds16(src0 + (size_t)r * rstep,
                    (char*)&As[0][0] + r * 4096 + wave * 1024);
    asm volatile("s_waitcnt vmcnt(0)" ::: "memory");
    __syncthreads();

    int cur = 0;
    for (int kt = 0; kt < NT; ++kt) {
        if (kt + 1 < NT) {
            const float* snext = src0 + (size_t)(kt + 1) * BK;
            #pragma unroll
            for (int r = 0; r < 4; ++r)
                gload_lds16(snext + (size_t)r * rstep,
                            (char*)&As[cur ^ 1][0] + r * 4096 + wave * 1024);
        }

        const char* Ab = (const char*)&As[cur][0] + arow * 256;
        const __bf16* bkp = bp + (size_t)kt * BK;
        #pragma unroll
        for (int kk = 0; kk < 2; ++kk) {
            f32x4 alo = *(const f32x4*)(Ab + (((kk * 8 + kg * 2 + 0) ^ r15) * 16));
            f32x4 ahi = *(const f32x4*)(Ab + (((kk * 8 + kg * 2 + 1) ^ r15) * 16));
            bf16x8 af;
            af[0] = (__bf16)alo[0]; af[1] = (__bf16)alo[1];
            af[2] = (__bf16)alo[2]; af[3] = (__bf16)alo[3];
            af[4] = (__bf16)ahi[0]; af[5] = (__bf16)ahi[1];
            af[6] = (__bf16)ahi[2]; af[7] = (__bf16)ahi[3];
            bf16x8 b0v = *(const bf16x8*)(bkp + kk * 32);
            bf16x8 b1v = *(const bf16x8*)(bkp + kk * 32 + 16 * (size_t)NN);
            bf16x8 b2v = *(const bf16x8*)(bkp + kk * 32 + 32 * (size_t)NN);
            bf16x8 b3v = *(const bf16x8*)(bkp + kk * 32 + 48 * (size_t)NN);
            acc0 = __builtin_amdgcn_mfma_f32_16x16x32_bf16(af, b0v, acc0, 0, 0, 0);
            acc1 = __builtin_amdgcn_mfma_f32_16x16x32_bf16(af, b1v, acc1, 0, 0, 0);
            acc2 = __builtin_amdgcn_mfma_f32_16x16x32_bf16(af, b2v, acc2, 0, 0, 0);
            acc3 = __builtin_amdgcn_mfma_f32_16x16x32_bf16(af, b3v, acc3, 0, 0, 0);
        }
        __syncthreads();   // drains vmcnt -> next buffer ready
        cur ^= 1;
    }

    float* pp = part + (size_t)s * NN * HID;
    const int rbase = m0 + wave * 16 + kg * 4;
    f32x4 accs[4] = {acc0, acc1, acc2, acc3};
    #pragma unroll
    for (int tt = 0; tt < 4; ++tt) {
        #pragma unroll
        for (int j = 0; j < 4; ++j) {
            pp[(size_t)(rbase + j) * HID + tt * 16 + r15] = accs[tt][j];
        }
    }
}

// ---------------------------------------------------------------------------
// Kernel 3: agg = sum(part[0..3]); combined=[x,agg];
// out = (tanh(tanh(combined@U1+c1)@U2+c2)) @ Wo + bo.  64 nodes/block.
// ---------------------------------------------------------------------------
__global__ __launch_bounds__(256) void k_update(
    const float* __restrict__ x, const float* __restrict__ part,
    const float* __restrict__ U1, const float* __restrict__ c1,
    const float* __restrict__ U2, const float* __restrict__ c2,
    const float* __restrict__ Wo, const float* __restrict__ bo,
    float* __restrict__ out)
{
    __shared__ float comb[64 * 73];
    __shared__ float h1s[64 * 66];

    const int t = threadIdx.x, h = t & 63, g = t >> 6;
    const int node0 = blockIdx.x * 64;

    comb[(t >> 2) * 73 + (t & 3)] = x[node0 * 4 + t];
    const float* P0 = part;
    const float* P1 = part + (size_t)1 * NN * HID;
    const float* P2 = part + (size_t)2 * NN * HID;
    const float* P3 = part + (size_t)3 * NN * HID;
    for (int n = g * 16; n < g * 16 + 16; ++n) {
        const size_t idx = (size_t)(node0 + n) * HID + h;
        comb[n * 73 + 4 + h] = P0[idx] + P1[idx] + P2[idx] + P3[idx];
    }
    __syncthreads();
    for (int n = g * 16; n < g * 16 + 16; ++n) {
        float acc = c1[h];
        #pragma unroll 4
        for (int k = 0; k < 68; ++k) acc += comb[n * 73 + k] * U1[k * 64 + h];
        h1s[n * 66 + h] = tanhf(acc);
    }
    __syncthreads();
    for (int n = g * 16; n < g * 16 + 16; ++n) {
        float acc = c2[h];
        #pragma unroll 8
        for (int k = 0; k < 64; ++k) acc += h1s[n * 66 + k] * U2[k * 64 + h];
        comb[n * 73 + h] = tanhf(acc);
    }
    __syncthreads();
    if (t < 128) {
        const int n = t >> 1, o = t & 1;
        float acc = bo[o];
        #pragma unroll 8
        for (int k = 0; k < 64; ++k) acc += comb[n * 73 + k] * Wo[k * 2 + o];
        out[(size_t)(node0 + n) * 2 + o] = acc;
    }
}

// ---------------------------------------------------------------------------
extern "C" void kernel_launch(void* const* d_in, const int* in_sizes, int n_in,
                              void* d_out, int out_size, void* d_ws, size_t ws_size,
                              hipStream_t stream)
{
    const float* x   = (const float*)d_in[0];
    const float* adj = (const float*)d_in[1];
    const float* W1  = (const float*)d_in[2];
    const float* b1  = (const float*)d_in[3];
    const float* W2  = (const float*)d_in[4];
    const float* b2  = (const float*)d_in[5];
    const float* U1  = (const float*)d_in[6];
    const float* c1  = (const float*)d_in[7];
    const float* U2  = (const float*)d_in[8];
    const float* c2  = (const float*)d_in[9];
    const float* Wo  = (const float*)d_in[10];
    const float* bo  = (const float*)d_in[11];
    float* out = (float*)d_out;

    __bf16* msgT = (__bf16*)d_ws;
    float*  part = (float*)((char*)d_ws + (size_t)HID * NN * sizeof(__bf16));

    k_messages<<<NN / 64, 256, 0, stream>>>(x, W1, b1, W2, b2, msgT);
    k_agg<<<256 * SPLITS, 256, 0, stream>>>(adj, msgT, part);
    k_update<<<NN / 64, 256, 0, stream>>>(x, part, U1, c1, U2, c2, Wo, bo, out);
}